// Round 8
// baseline (152.451 us; speedup 1.0000x reference)
//
#include <hip/hip_runtime.h>

// ---------- types / helpers ----------
typedef __attribute__((ext_vector_type(8))) short short8;   // 8 bf16 = 4 VGPRs
typedef __attribute__((ext_vector_type(4))) float floatx4;  // MFMA C/D 16x16
typedef __attribute__((ext_vector_type(16))) float f32x16;  // MFMA C/D 32x32
typedef __attribute__((ext_vector_type(4))) float f32x4;
typedef __attribute__((ext_vector_type(2))) unsigned uint2v;

__device__ __forceinline__ short f2bf(float f) {
    union { float f; unsigned u; } v;
    v.f = f;
    unsigned r = v.u + 0x7fffu + ((v.u >> 16) & 1u);  // RNE
    return (short)(r >> 16);
}

#define MFMA_BF16(a, b, c) __builtin_amdgcn_mfma_f32_16x16x32_bf16((a), (b), (c), 0, 0, 0)
#define MFMA32(a, b, c)    __builtin_amdgcn_mfma_f32_32x32x16_bf16((a), (b), (c), 0, 0, 0)

__device__ __forceinline__ float fast_exp2(float x) {
#if __has_builtin(__builtin_amdgcn_exp2f)
    return __builtin_amdgcn_exp2f(x);
#else
    return exp2f(x);
#endif
}

// v_cvt_pk_bf16_f32: lo -> [15:0], hi -> [31:16], RNE
__device__ __forceinline__ unsigned cvtpk(float lo, float hi) {
    unsigned r;
    asm("v_cvt_pk_bf16_f32 %0, %1, %2" : "=v"(r) : "v"(lo), "v"(hi));
    return r;
}

// v_permlane32_swap_b32: new_a = (aL, bL), new_b = (aH, bH)  [asm-only; ISA-verified]
__device__ __forceinline__ void pl32(unsigned& a, unsigned& b) {
    asm("v_permlane32_swap_b32 %0, %1" : "+v"(a), "+v"(b));
}

// async global->LDS, 16B per lane; LDS dest must be the WAVE-UNIFORM base;
// HW places lane i's 16B at base + i*16.
__device__ __forceinline__ void gll16(const void* g, void* l) {
    __builtin_amdgcn_global_load_lds((const __attribute__((address_space(1))) void*)g,
                                     (__attribute__((address_space(3))) void*)l,
                                     16, 0, 0);
}

// scale(1/8) * log2(e): softmax in exp2 domain, folded into Q at proj time
#define QSCALE_LOG2E 0.18033688011112042f

// ---------- 1) weights -> fragment-native WF[(k/8)][n][8], bf16 ----------
__global__ __launch_bounds__(256) void wfrag_all(const float* __restrict__ Wq,
                                                 const float* __restrict__ Wk,
                                                 const float* __restrict__ Wv,
                                                 const float* __restrict__ Wo,
                                                 short* __restrict__ WqF,
                                                 short* __restrict__ WkF,
                                                 short* __restrict__ WvF,
                                                 short* __restrict__ WoF) {
    const int z = blockIdx.y;
    const float* src = (z == 0) ? Wq : (z == 1) ? Wk : (z == 2) ? Wv : Wo;
    short* dst = (z == 0) ? WqF : (z == 1) ? WkF : (z == 2) ? WvF : WoF;
    const int nbits = (z < 3) ? 9 : 10;          // N = 512 or 1024
    const int N = 1 << nbits;
    const int t = blockIdx.x * 256 + threadIdx.x;  // 0..65535
    const int kb = t >> nbits;
    const int n = t & (N - 1);
    const float* s = src + (size_t)(kb * 8) * N + n;
    short8 v;
#pragma unroll
    for (int j = 0; j < 8; ++j) v[j] = f2bf(s[(size_t)j * N]);
    *(short8*)(dst + (size_t)t * 8) = v;
}

// ---------- 2) activations -> fragment-native AF[(k/8)][row][8], bf16 ----------
__global__ __launch_bounds__(256) void afrag(const float* __restrict__ x,
                                             const float* __restrict__ ctx,
                                             short* __restrict__ AxF,
                                             short* __restrict__ AcF) {
    const float* src = (blockIdx.z == 0) ? x : ctx;
    short* dst = (blockIdx.z == 0) ? AxF : AcF;
    const int r0 = blockIdx.x * 64;
    const int k0 = blockIdx.y * 64;
    __shared__ short tile[64][72];
    const int tid = threadIdx.x;
    {
        const int seg = tid & 15;        // 16 x f32x4 per row
        const int rbase = tid >> 4;      // 0..15
#pragma unroll
        for (int i = 0; i < 4; ++i) {
            const int row = rbase + i * 16;
            f32x4 v = *(const f32x4*)(src + (size_t)(r0 + row) * 1024 + k0 + seg * 4);
            uint2v d;
            d[0] = cvtpk(v[0], v[1]);   // RNE, same as f2bf
            d[1] = cvtpk(v[2], v[3]);
            *(uint2v*)&tile[row][seg * 4] = d;   // 8B ds_write_b64
        }
    }
    __syncthreads();
    {
        const int kbl = tid >> 5;        // 0..7
        const int rbase = tid & 31;
#pragma unroll
        for (int j = 0; j < 2; ++j) {
            const int row = rbase + j * 32;
            short8 v = *(const short8*)(&tile[row][kbl * 8]);
            *(short8*)(dst + ((size_t)(k0 / 8 + kbl) * 4096 + r0 + row) * 8) = v;
        }
    }
}

// ---------- 3) QKV projection GEMM: LDS-staged 2-phase; z=2 epilogue via LDS ----------
// BM=64, BN=128, BK=64 (8 kb). 4 waves (2x2), wave-tile 32x64, acc[2][4].
// z=2 (V^T) output is transposed [h][d][n]: direct stores were 2-B scatter at
// 4-KB stride (~16x sector write amplification). Route through the free 48 KB
// LDS after the K-loop -> 64-B contiguous global writes. Values bit-identical.
__global__ __launch_bounds__(256) void gemm_qkv(const short* __restrict__ AxF,
                                                const short* __restrict__ AcF,
                                                const short* __restrict__ WqF,
                                                const short* __restrict__ WkF,
                                                const short* __restrict__ WvF,
                                                short* __restrict__ Qw,
                                                short* __restrict__ Kw,
                                                short* __restrict__ Vtw) {
    const int z = blockIdx.z;
    const short* AF = (z == 0) ? AxF : AcF;
    const short* WF = (z == 0) ? WqF : (z == 1) ? WkF : WvF;
    const int tid = threadIdx.x;
    const int w = tid >> 6;
    const int lane = tid & 63;
    const int quad = lane >> 4, ln = lane & 15;
    const int wr = w >> 1, wc = w & 1;
    const int row0 = blockIdx.x * 64;
    const int col0 = blockIdx.y * 128;

    // [buf][ A: 8kb x 64 x 8 = 4096 shorts | B: 8kb x 128 x 8 = 8192 shorts ]
    __shared__ __align__(16) short lds[2][12288];   // 48 KB

    auto stage = [&](int buf, int kt) {
        short* d = &lds[buf][0];
        const int kb0 = kt * 8;
#pragma unroll
        for (int c = 0; c < 2; ++c) {
            const int kb = c * 4 + w;
            gll16(AF + ((size_t)(kb0 + kb) * 4096 + row0 + lane) * 8,
                  d + kb * 512);
        }
#pragma unroll
        for (int c = 0; c < 4; ++c) {
            const int g = c * 4 + w;
            const int kb = g >> 1, colb = (g & 1) * 64;
            gll16(WF + ((size_t)(kb0 + kb) * 512 + col0 + colb + lane) * 8,
                  d + 4096 + (kb * 128 + colb) * 8);
        }
    };

    floatx4 acc[2][4] = {};

    auto compute = [&](int buf) {
        const short* sA = &lds[buf][0];
        const short* sB = &lds[buf][4096];
#pragma unroll
        for (int s = 0; s < 2; ++s) {
            const int kb = s * 4 + quad;
            short8 aF[2], bF[4];
#pragma unroll
            for (int i = 0; i < 2; ++i)
                aF[i] = *(const short8*)(sA + (kb * 64 + wr * 32 + i * 16 + ln) * 8);
#pragma unroll
            for (int j = 0; j < 4; ++j)
                bF[j] = *(const short8*)(sB + (kb * 128 + wc * 64 + j * 16 + ln) * 8);
#pragma unroll
            for (int i = 0; i < 2; ++i)
#pragma unroll
                for (int j = 0; j < 4; ++j)
                    acc[i][j] = MFMA_BF16(aF[i], bF[j], acc[i][j]);
        }
    };

    stage(0, 0);
    __syncthreads();                       // compiler drains vmcnt before barrier
    for (int t = 0; t < 16; ++t) {
        if (t + 1 < 16) stage((t + 1) & 1, t + 1);
        compute(t & 1);
        __syncthreads();
    }

    const float oscale = (z == 0) ? QSCALE_LOG2E : 1.0f;
    if (z < 2) {
        short* dst = (z == 0) ? Qw : Kw;
#pragma unroll
        for (int i = 0; i < 2; ++i)
#pragma unroll
            for (int t = 0; t < 4; ++t)
#pragma unroll
                for (int r = 0; r < 4; ++r) {
                    const int R = row0 + wr * 32 + i * 16 + quad * 4 + r;
                    const int C = col0 + wc * 64 + t * 16 + ln;
                    const int b = R >> 11, n = R & 2047;
                    const int h = C >> 6, d = C & 63;
                    dst[((b * 8 + h) * 2048 + n) * 64 + d] = f2bf(acc[i][t][r] * oscale);
                }
    } else {
        // LDS transpose: t2[lc 128][72 pad] bf16, then 64-B contiguous writes.
        short* t2 = (short*)&lds[0][0];   // loop's final barrier orders reads before this
#pragma unroll
        for (int i = 0; i < 2; ++i)
#pragma unroll
            for (int t = 0; t < 4; ++t)
#pragma unroll
                for (int r = 0; r < 4; ++r) {
                    const int lr = wr * 32 + i * 16 + quad * 4 + r;
                    const int lc = wc * 64 + t * 16 + ln;
                    t2[lc * 72 + lr] = f2bf(acc[i][t][r]);
                }
        __syncthreads();
        const int c = tid >> 1, halfr = (tid & 1) * 32;
        const int C = col0 + c;
        const int h = C >> 6, d = C & 63;
        const int b = row0 >> 11;
        const int n0 = (row0 & 2047) + halfr;
        short* gp = Vtw + (((size_t)(b * 8 + h) * 64 + d) * 2048) + n0;
        const short* sp = t2 + c * 72 + halfr;
#pragma unroll
        for (int u = 0; u < 4; ++u)
            *(short8*)(gp + u * 8) = *(const short8*)(sp + u * 8);
    }
}

// ---------- 4) flash attention: QBLK=128, 8 waves (q-half x kv-rotation) ----------
// Wave w: q-half = w&1 (64 rows), kv rotation = w>>1 (tiles kvr+4t). Inner loop
// identical to the verified round-5 kernel. L2 KV traffic halves vs QBLK=64
// (256 blocks x 512 KB = 128 MB). LDS 128 KB -> 1 block/CU, 8 waves = 2/SIMD
// (same occupancy as before). Two independent 4-way merges at the end.
__global__ __launch_bounds__(512, 1) void attn_kernel(const short* __restrict__ Q,
                                                      const short* __restrict__ K,
                                                      const short* __restrict__ Vt,
                                                      short* __restrict__ AwF) {
    const int tid = threadIdx.x;
    const int w = tid >> 6;           // 0..7
    const int lane = tid & 63;
    const int hi = lane >> 5;         // 0/1
    const int ln5 = lane & 31;        // 0..31
    const int qh = w & 1;             // q-half within the 128-row block
    const int kvr = w >> 1;           // kv rotation index 0..3

    // Bijective XCD swizzle (T1): all 16 q-blocks of a bh land on one XCD.
    const int L = blockIdx.x + 16 * blockIdx.y;   // grid (16,16) -> 0..255
    const int xcd = L & 7, slot = L >> 3;         // slot 0..31
    const int bh = xcd * 2 + (slot >> 4);         // 0..15
    const int q0 = (slot & 15) * 128;

    // 128 KB: per-wave 16KB region: [buf0: K 4KB | V 4KB][buf1: K 4KB | V 4KB]
    __shared__ __align__(16) char smem[131072];
    char* const wbase = smem + w * 16384;

    const short* Qbh = Q + (size_t)bh * 2048 * 64;
    const char* kp = (const char*)(K + (size_t)bh * 2048 * 64);   // [n][128B]
    const char* vp = (const char*)(Vt + (size_t)bh * 64 * 2048);  // [d][4096B]

    const int qbase = q0 + qh * 64;
    short8 qf[2][4];
#pragma unroll
    for (int qt = 0; qt < 2; ++qt)
#pragma unroll
        for (int ds = 0; ds < 4; ++ds)
            qf[qt][ds] = *(const short8*)(Qbh + (size_t)(qbase + qt * 32 + ln5) * 64 + ds * 16 + hi * 8);

    f32x16 O[2][2] = {};  // [dt][qt]: row d = dt*32+(e&3)+8*(e>>2)+4*hi, col q = qt*32+ln5
    float lp0 = 0.f, lp1 = 0.f;

    const int lrow = lane >> 3, lu = lane & 7;
    const int swzK = ((lu ^ lrow) << 4);
    const int sw_r = (ln5 & 7) << 4;  // read-side XOR key

    auto stageK = [&](int tile, int c) {
        char* kb = wbase + c * 8192;
#pragma unroll
        for (int i = 0; i < 4; ++i)
            gll16(kp + (size_t)tile * 4096 + (size_t)i * 1024 + lrow * 128 + swzK,
                  kb + i * 1024);
    };
    auto stageV = [&](int tile, int c) {
        char* vb = wbase + c * 8192 + 4096;
#pragma unroll
        for (int i = 0; i < 4; ++i) {
            const int u = lu ^ lrow;                    // logical unit 0..7
            const int d = i * 8 + lrow + 32 * (u >> 2); // d row 0..63
            gll16(vp + (size_t)d * 4096 + (size_t)tile * 64 + (u & 3) * 16,
                  vb + i * 1024);
        }
    };

    short8 PA[2][2];  // [kb][qt] PV B-operand fragments

    auto computeTile = [&](int c) {
        char* kb = wbase + c * 8192;
        char* vb = kb + 4096;
        short8 kf[4];
#pragma unroll
        for (int ds = 0; ds < 4; ++ds)
            kf[ds] = *(const short8*)(kb + ln5 * 128 + ((((ds * 2 + hi) << 4)) ^ sw_r));
        short8 vf[2][2];
#pragma unroll
        for (int dt = 0; dt < 2; ++dt)
#pragma unroll
            for (int k2 = 0; k2 < 2; ++k2)
                vf[dt][k2] = *(const short8*)(vb + ln5 * 128 +
                                              ((((dt * 4 + k2 * 2 + hi) << 4)) ^ sw_r));
        f32x16 s0 = {}, s1 = {};
        __builtin_amdgcn_s_setprio(1);
#pragma unroll
        for (int ds = 0; ds < 4; ++ds) {
            s0 = MFMA32(kf[ds], qf[0][ds], s0);
            s1 = MFMA32(kf[ds], qf[1][ds], s1);
        }
        __builtin_amdgcn_s_setprio(0);
        auto buildPA = [&](const f32x16& sv, float& lacc, short8& oA, short8& oB) {
            float p[16];
#pragma unroll
            for (int e = 0; e < 16; ++e) p[e] = fast_exp2(sv[e]);
            float t0 = 0.f, t1 = 0.f;
#pragma unroll
            for (int e = 0; e < 16; e += 2) { t0 += p[e]; t1 += p[e + 1]; }
            lacc += t0 + t1;
            unsigned c0 = cvtpk(p[0], p[1]),   c1 = cvtpk(p[2], p[3]);
            unsigned c2 = cvtpk(p[4], p[5]),   c3 = cvtpk(p[6], p[7]);
            unsigned c4 = cvtpk(p[8], p[9]),   c5 = cvtpk(p[10], p[11]);
            unsigned c6 = cvtpk(p[12], p[13]), c7 = cvtpk(p[14], p[15]);
            pl32(c0, c2); pl32(c1, c3);
            pl32(c4, c6); pl32(c5, c7);
            union U { short8 s8; unsigned u[4]; };
            U a; a.u[0] = c0; a.u[1] = c1; a.u[2] = c2; a.u[3] = c3; oA = a.s8;
            U b; b.u[0] = c4; b.u[1] = c5; b.u[2] = c6; b.u[3] = c7; oB = b.s8;
        };
        buildPA(s0, lp0, PA[0][0], PA[1][0]);
        buildPA(s1, lp1, PA[0][1], PA[1][1]);
        __builtin_amdgcn_s_setprio(1);
#pragma unroll
        for (int dt = 0; dt < 2; ++dt)
#pragma unroll
            for (int k2 = 0; k2 < 2; ++k2) {
                O[dt][0] = MFMA32(vf[dt][k2], PA[k2][0], O[dt][0]);
                O[dt][1] = MFMA32(vf[dt][k2], PA[k2][1], O[dt][1]);
            }
        __builtin_amdgcn_s_setprio(0);
    };

    // ---- main loop: NO barriers; wave-local counted vmcnt (T4) ----
    stageK(kvr, 0);
    stageV(kvr, 0);
    int cur = 0;
    for (int t = 0; t < 16; ++t) {
        if (t < 15) {
            stageK(kvr + (t + 1) * 4, cur ^ 1);
            stageV(kvr + (t + 1) * 4, cur ^ 1);
            asm volatile("s_waitcnt vmcnt(8)" ::: "memory");
        } else {
            asm volatile("s_waitcnt vmcnt(0)" ::: "memory");
        }
        computeTile(cur);
        cur ^= 1;
    }
    __syncthreads();  // waves decoupled; merge below reuses smem

    // ---- merge: two independent 4-way (over kvr) reductions, one per q-half ----
    float* lpf = (float*)smem;  // [2 group][4 member][64 q]
    {
        const float a = lp0 + __shfl_xor(lp0, 32);
        const float b = lp1 + __shfl_xor(lp1, 32);
        if (hi == 0) {
            lpf[(qh * 4 + kvr) * 64 + ln5] = a;
            lpf[(qh * 4 + kvr) * 64 + 32 + ln5] = b;
        }
    }
    __syncthreads();
    const int qq = tid & 127;       // 0..127 within the 128-row block
    const int k8a = tid >> 7;       // 0..3
    const int g = qq >> 6, qr = qq & 63;
    const float den = lpf[(g * 4 + 0) * 64 + qr] + lpf[(g * 4 + 1) * 64 + qr] +
                      lpf[(g * 4 + 2) * 64 + qr] + lpf[(g * 4 + 3) * 64 + qr];
    const float inv = 1.0f / den;
    __syncthreads();
    float* freg = (float*)smem + w * 4096;  // wave's 16KB region: [64 d][64 q] f32
#pragma unroll
    for (int dt = 0; dt < 2; ++dt)
#pragma unroll
        for (int qt = 0; qt < 2; ++qt)
#pragma unroll
            for (int e = 0; e < 16; ++e) {
                const int d = dt * 32 + (e & 3) + 8 * (e >> 2) + 4 * hi;
                freg[d * 64 + qt * 32 + ln5] = O[dt][qt][e];
            }
    __syncthreads();
    const int b = bh >> 3, h = bh & 7;
    const float* fall = (const float*)smem;
#pragma unroll
    for (int j = 0; j < 2; ++j) {
        const int k8 = k8a + j * 4;  // 0..7
        float a8[8];
#pragma unroll
        for (int dd = 0; dd < 8; ++dd) {
            const int d = k8 * 8 + dd;
            a8[dd] = fall[(g + 0) * 4096 + d * 64 + qr] + fall[(g + 2) * 4096 + d * 64 + qr] +
                     fall[(g + 4) * 4096 + d * 64 + qr] + fall[(g + 6) * 4096 + d * 64 + qr];
        }
        short8 o8;
#pragma unroll
        for (int dd = 0; dd < 8; ++dd) o8[dd] = f2bf(a8[dd] * inv);
        *(short8*)(AwF + ((size_t)(h * 8 + k8) * 4096 + (size_t)(b * 2048 + q0 + qq)) * 8) = o8;
    }
}

// ---------- 5) output GEMM: LDS-staged (round-7 version, unchanged) ----------
__global__ __launch_bounds__(256) void gemm_final(const short* __restrict__ AwF,
                                                  const short* __restrict__ WoF,
                                                  const float* __restrict__ bias,
                                                  float* __restrict__ out) {
    const int tid = threadIdx.x;
    const int w = tid >> 6;
    const int lane = tid & 63;
    const int quad = lane >> 4, ln = lane & 15;
    const int wr = w >> 1, wc = w & 1;
    const int row0 = blockIdx.x * 64;
    const int col0 = blockIdx.y * 128;

    __shared__ __align__(16) short lds[2][12288];   // 48 KB

    auto stage = [&](int buf, int kt) {
        short* d = &lds[buf][0];
        const int kb0 = kt * 8;
#pragma unroll
        for (int c = 0; c < 2; ++c) {
            const int kb = c * 4 + w;
            gll16(AwF + ((size_t)(kb0 + kb) * 4096 + row0 + lane) * 8,
                  d + kb * 512);
        }
#pragma unroll
        for (int c = 0; c < 4; ++c) {
            const int g = c * 4 + w;
            const int kb = g >> 1, colb = (g & 1) * 64;
            gll16(WoF + ((size_t)(kb0 + kb) * 1024 + col0 + colb + lane) * 8,
                  d + 4096 + (kb * 128 + colb) * 8);
        }
    };

    floatx4 acc[2][4] = {};

    auto compute = [&](int buf) {
        const short* sA = &lds[buf][0];
        const short* sB = &lds[buf][4096];
#pragma unroll
        for (int s = 0; s < 2; ++s) {
            const int kb = s * 4 + quad;
            short8 aF[2], bF[4];
#pragma unroll
            for (int i = 0; i < 2; ++i)
                aF[i] = *(const short8*)(sA + (kb * 64 + wr * 32 + i * 16 + ln) * 8);
#pragma unroll
            for (int j = 0; j < 4; ++j)
                bF[j] = *(const short8*)(sB + (kb * 128 + wc * 64 + j * 16 + ln) * 8);
#pragma unroll
            for (int i = 0; i < 2; ++i)
#pragma unroll
                for (int j = 0; j < 4; ++j)
                    acc[i][j] = MFMA_BF16(aF[i], bF[j], acc[i][j]);
        }
    };

    stage(0, 0);
    __syncthreads();
    for (int t = 0; t < 8; ++t) {
        if (t + 1 < 8) stage((t + 1) & 1, t + 1);
        compute(t & 1);
        __syncthreads();
    }

#pragma unroll
    for (int i = 0; i < 2; ++i)
#pragma unroll
        for (int t = 0; t < 4; ++t)
#pragma unroll
            for (int r = 0; r < 4; ++r) {
                const int R = row0 + wr * 32 + i * 16 + quad * 4 + r;
                const int C = col0 + wc * 64 + t * 16 + ln;
                out[(size_t)R * 1024 + C] = acc[i][t][r] + bias[C];
            }
}

// ---------- launcher ----------
extern "C" void kernel_launch(void* const* d_in, const int* in_sizes, int n_in,
                              void* d_out, int out_size, void* d_ws, size_t ws_size,
                              hipStream_t stream) {
    const float* x   = (const float*)d_in[0];  // [2,2048,1024] f32
    const float* ctx = (const float*)d_in[1];
    const float* Wq  = (const float*)d_in[2];  // [1024,512]
    const float* Wk  = (const float*)d_in[3];
    const float* Wv  = (const float*)d_in[4];
    const float* Wo  = (const float*)d_in[5];  // [512,1024]
    const float* bo  = (const float*)d_in[6];  // [1024]
    float* out = (float*)d_out;                // [2,2048,1024] f32

    char* ws = (char*)d_ws;
    size_t off = 0;
    auto alloc = [&](size_t bytes) { char* p = ws + off; off += (bytes + 255) & ~(size_t)255; return p; };

    short* WqF  = (short*)alloc(512 * 1024 * 2);        // fragment-native bf16
    short* WkF  = (short*)alloc(512 * 1024 * 2);
    short* WvF  = (short*)alloc(512 * 1024 * 2);
    short* WoF  = (short*)alloc(1024 * 512 * 2);
    short* AxF  = (short*)alloc((size_t)4096 * 1024 * 2);  // x native
    short* AcF  = (short*)alloc((size_t)4096 * 1024 * 2);  // ctx native
    short* Qw   = (short*)alloc((size_t)16 * 2048 * 64 * 2);
    short* Kw   = (short*)alloc((size_t)16 * 2048 * 64 * 2);
    short* Vtw  = (short*)alloc((size_t)16 * 2048 * 64 * 2);
    short* AwF  = (short*)alloc((size_t)4096 * 512 * 2);   // attn out, native

    wfrag_all<<<dim3(256, 4), 256, 0, stream>>>(Wq, Wk, Wv, Wo, WqF, WkF, WvF, WoF);
    afrag<<<dim3(64, 16, 2), 256, 0, stream>>>(x, ctx, AxF, AcF);

    gemm_qkv<<<dim3(64, 4, 3), 256, 0, stream>>>(AxF, AcF, WqF, WkF, WvF, Qw, Kw, Vtw);

    attn_kernel<<<dim3(16, 16), 512, 0, stream>>>(Qw, Kw, Vtw, AwF);

    gemm_final<<<dim3(64, 8), 256, 0, stream>>>(AwF, WoF, bo, out);
}

// Round 9
// 149.587 us; speedup vs baseline: 1.0192x; 1.0192x over previous
//
#include <hip/hip_runtime.h>

// ---------- types / helpers ----------
typedef __attribute__((ext_vector_type(8))) short short8;   // 8 bf16 = 4 VGPRs
typedef __attribute__((ext_vector_type(4))) float floatx4;  // MFMA C/D 16x16
typedef __attribute__((ext_vector_type(16))) float f32x16;  // MFMA C/D 32x32
typedef __attribute__((ext_vector_type(4))) float f32x4;
typedef __attribute__((ext_vector_type(2))) unsigned uint2v;

__device__ __forceinline__ short f2bf(float f) {
    union { float f; unsigned u; } v;
    v.f = f;
    unsigned r = v.u + 0x7fffu + ((v.u >> 16) & 1u);  // RNE
    return (short)(r >> 16);
}

#define MFMA_BF16(a, b, c) __builtin_amdgcn_mfma_f32_16x16x32_bf16((a), (b), (c), 0, 0, 0)
#define MFMA32(a, b, c)    __builtin_amdgcn_mfma_f32_32x32x16_bf16((a), (b), (c), 0, 0, 0)

__device__ __forceinline__ float fast_exp2(float x) {
#if __has_builtin(__builtin_amdgcn_exp2f)
    return __builtin_amdgcn_exp2f(x);
#else
    return exp2f(x);
#endif
}

// v_cvt_pk_bf16_f32: lo -> [15:0], hi -> [31:16], RNE
__device__ __forceinline__ unsigned cvtpk(float lo, float hi) {
    unsigned r;
    asm("v_cvt_pk_bf16_f32 %0, %1, %2" : "=v"(r) : "v"(lo), "v"(hi));
    return r;
}

// v_permlane32_swap_b32: new_a = (aL, bL), new_b = (aH, bH)  [asm-only; ISA-verified]
__device__ __forceinline__ void pl32(unsigned& a, unsigned& b) {
    asm("v_permlane32_swap_b32 %0, %1" : "+v"(a), "+v"(b));
}

// async global->LDS, 16B per lane; LDS dest must be the WAVE-UNIFORM base;
// HW places lane i's 16B at base + i*16.
__device__ __forceinline__ void gll16(const void* g, void* l) {
    __builtin_amdgcn_global_load_lds((const __attribute__((address_space(1))) void*)g,
                                     (__attribute__((address_space(3))) void*)l,
                                     16, 0, 0);
}

// scale(1/8) * log2(e): softmax in exp2 domain, folded into Q at proj time
#define QSCALE_LOG2E 0.18033688011112042f

// ---------- 1) weights -> fragment-native WF[(k/8)][n][8], bf16 ----------
__global__ __launch_bounds__(256) void wfrag_all(const float* __restrict__ Wq,
                                                 const float* __restrict__ Wk,
                                                 const float* __restrict__ Wv,
                                                 const float* __restrict__ Wo,
                                                 short* __restrict__ WqF,
                                                 short* __restrict__ WkF,
                                                 short* __restrict__ WvF,
                                                 short* __restrict__ WoF) {
    const int z = blockIdx.y;
    const float* src = (z == 0) ? Wq : (z == 1) ? Wk : (z == 2) ? Wv : Wo;
    short* dst = (z == 0) ? WqF : (z == 1) ? WkF : (z == 2) ? WvF : WoF;
    const int nbits = (z < 3) ? 9 : 10;          // N = 512 or 1024
    const int N = 1 << nbits;
    const int t = blockIdx.x * 256 + threadIdx.x;  // 0..65535
    const int kb = t >> nbits;
    const int n = t & (N - 1);
    const float* s = src + (size_t)(kb * 8) * N + n;
    short8 v;
#pragma unroll
    for (int j = 0; j < 8; ++j) v[j] = f2bf(s[(size_t)j * N]);
    *(short8*)(dst + (size_t)t * 8) = v;
}

// ---------- 2) FUSED QKV projection GEMM: afrag folded in ----------
// BM=64, BN=128, BK=64. A is read as f32 from x/ctx and converted in-kernel
// (T14 split: global_load f32x4 issued BEFORE compute, cvt+ds_write AFTER).
// A LDS tile [64][72] bf16: 144-B row stride keeps 16-B alignment; bank
// histogram uniform (4/bank on b64 write, 8/bank on b128 read). B staged via
// global_load_lds, fragment-native. Values bit-identical to the afrag path.
__global__ __launch_bounds__(256) void gemm_qkv(const float* __restrict__ x,
                                                const float* __restrict__ ctx,
                                                const short* __restrict__ WqF,
                                                const short* __restrict__ WkF,
                                                const short* __restrict__ WvF,
                                                short* __restrict__ Qw,
                                                short* __restrict__ Kw,
                                                short* __restrict__ Vtw) {
    const int z = blockIdx.z;
    const float* As = (z == 0) ? x : ctx;
    const short* WF = (z == 0) ? WqF : (z == 1) ? WkF : WvF;
    const int tid = threadIdx.x;
    const int w = tid >> 6;
    const int lane = tid & 63;
    const int quad = lane >> 4, ln = lane & 15;
    const int wr = w >> 1, wc = w & 1;
    const int row0 = blockIdx.x * 64;
    const int col0 = blockIdx.y * 128;

    // layout: A bufs 2 x [64][72] = 9216 shorts | B bufs 2 x 8192 shorts
    __shared__ __align__(16) short lds[25600];   // 51.2 KB -> 3 blocks/CU
    auto aP = [&](int buf) { return lds + buf * 4608; };
    auto bP = [&](int buf) { return lds + 9216 + buf * 8192; };

    const int seg = tid & 15;        // 16 segs x 4 k
    const int rb = tid >> 4;         // 0..15

    auto loadA = [&](int kt, f32x4* vn) {
#pragma unroll
        for (int i = 0; i < 4; ++i)
            vn[i] = *(const f32x4*)(As + (size_t)(row0 + rb + i * 16) * 1024 + kt * 64 + seg * 4);
    };
    auto writeA = [&](int buf, const f32x4* vn) {
        short* a = aP(buf);
#pragma unroll
        for (int i = 0; i < 4; ++i) {
            uint2v d;
            d[0] = cvtpk(vn[i][0], vn[i][1]);
            d[1] = cvtpk(vn[i][2], vn[i][3]);
            *(uint2v*)(a + (rb + i * 16) * 72 + seg * 4) = d;
        }
    };
    auto stageB = [&](int buf, int kt) {
        short* d = bP(buf);
        const int kb0 = kt * 8;
#pragma unroll
        for (int c = 0; c < 4; ++c) {
            const int g = c * 4 + w;
            const int kb = g >> 1, colb = (g & 1) * 64;
            gll16(WF + ((size_t)(kb0 + kb) * 512 + col0 + colb + lane) * 8,
                  d + (kb * 128 + colb) * 8);
        }
    };

    floatx4 acc[2][4] = {};

    auto compute = [&](int buf) {
        const short* sA = aP(buf);
        const short* sB = bP(buf);
#pragma unroll
        for (int s = 0; s < 2; ++s) {
            const int kb = s * 4 + quad;
            short8 aF[2], bF[4];
#pragma unroll
            for (int i = 0; i < 2; ++i)
                aF[i] = *(const short8*)(sA + (wr * 32 + i * 16 + ln) * 72 + kb * 8);
#pragma unroll
            for (int j = 0; j < 4; ++j)
                bF[j] = *(const short8*)(sB + (kb * 128 + wc * 64 + j * 16 + ln) * 8);
#pragma unroll
            for (int i = 0; i < 2; ++i)
#pragma unroll
                for (int j = 0; j < 4; ++j)
                    acc[i][j] = MFMA_BF16(aF[i], bF[j], acc[i][j]);
        }
    };

    {
        f32x4 v0[4];
        loadA(0, v0);
        stageB(0, 0);
        writeA(0, v0);
    }
    __syncthreads();                 // drains vmcnt (B) + lgkm (A writes)
    int cur = 0;
    for (int t = 0; t < 16; ++t) {
        f32x4 vn[4];
        const bool more = (t + 1 < 16);
        if (more) {
            loadA(t + 1, vn);        // issue early: latency hides under compute
            stageB(cur ^ 1, t + 1);
        }
        compute(cur);
        if (more) writeA(cur ^ 1, vn);  // write late (T14)
        __syncthreads();
        cur ^= 1;
    }

    const float oscale = (z == 0) ? QSCALE_LOG2E : 1.0f;
    if (z < 2) {
        short* dst = (z == 0) ? Qw : Kw;
#pragma unroll
        for (int i = 0; i < 2; ++i)
#pragma unroll
            for (int t = 0; t < 4; ++t)
#pragma unroll
                for (int r = 0; r < 4; ++r) {
                    const int R = row0 + wr * 32 + i * 16 + quad * 4 + r;
                    const int C = col0 + wc * 64 + t * 16 + ln;
                    const int b = R >> 11, n = R & 2047;
                    const int h = C >> 6, d = C & 63;
                    dst[((b * 8 + h) * 2048 + n) * 64 + d] = f2bf(acc[i][t][r] * oscale);
                }
    } else {
        // LDS transpose: t2[lc 128][72 pad] bf16, then 64-B contiguous writes.
        short* t2 = lds;   // loop's final barrier orders reads before this
#pragma unroll
        for (int i = 0; i < 2; ++i)
#pragma unroll
            for (int t = 0; t < 4; ++t)
#pragma unroll
                for (int r = 0; r < 4; ++r) {
                    const int lr = wr * 32 + i * 16 + quad * 4 + r;
                    const int lc = wc * 64 + t * 16 + ln;
                    t2[lc * 72 + lr] = f2bf(acc[i][t][r]);
                }
        __syncthreads();
        const int c = tid >> 1, halfr = (tid & 1) * 32;
        const int C = col0 + c;
        const int h = C >> 6, d = C & 63;
        const int b = row0 >> 11;
        const int n0 = (row0 & 2047) + halfr;
        short* gp = Vtw + (((size_t)(b * 8 + h) * 64 + d) * 2048) + n0;
        const short* sp = t2 + c * 72 + halfr;
#pragma unroll
        for (int u = 0; u < 4; ++u)
            *(short8*)(gp + u * 8) = *(const short8*)(sp + u * 8);
    }
}

// ---------- 3) flash attention (round-7 version: QBLK=64, wave-private KV) ----------
__global__ __launch_bounds__(256, 2) void attn_kernel(const short* __restrict__ Q,
                                                      const short* __restrict__ K,
                                                      const short* __restrict__ Vt,
                                                      short* __restrict__ AwF) {
    const int tid = threadIdx.x;
    const int w = tid >> 6;
    const int lane = tid & 63;
    const int hi = lane >> 5;         // 0/1
    const int ln5 = lane & 31;        // 0..31

    // Bijective XCD swizzle (T1): all 32 q-blocks of a bh land on one XCD.
    const int L = blockIdx.x + 32 * blockIdx.y;   // grid (32,16) -> 0..511
    const int xcd = L & 7, slot = L >> 3;         // slot 0..63
    const int bh = xcd * 2 + (slot >> 5);         // 0..15
    const int q0 = (slot & 31) * 64;

    // 64KB: per-wave 16KB region: [buf0: K 4KB | V 4KB][buf1: K 4KB | V 4KB]
    __shared__ __align__(16) char smem[65536];
    char* const wbase = smem + w * 16384;

    const short* Qbh = Q + (size_t)bh * 2048 * 64;
    const char* kp = (const char*)(K + (size_t)bh * 2048 * 64);   // [n][128B]
    const char* vp = (const char*)(Vt + (size_t)bh * 64 * 2048);  // [d][4096B]

    short8 qf[2][4];
#pragma unroll
    for (int qt = 0; qt < 2; ++qt)
#pragma unroll
        for (int ds = 0; ds < 4; ++ds)
            qf[qt][ds] = *(const short8*)(Qbh + (size_t)(q0 + qt * 32 + ln5) * 64 + ds * 16 + hi * 8);

    f32x16 O[2][2] = {};  // [dt][qt]: row d = dt*32+(e&3)+8*(e>>2)+4*hi, col q = qt*32+ln5
    float lp0 = 0.f, lp1 = 0.f;

    const int lrow = lane >> 3, lu = lane & 7;
    const int swzK = ((lu ^ lrow) << 4);
    const int sw_r = (ln5 & 7) << 4;  // read-side XOR key

    auto stageK = [&](int tile, int c) {
        char* kb = wbase + c * 8192;
#pragma unroll
        for (int i = 0; i < 4; ++i)
            gll16(kp + (size_t)tile * 4096 + (size_t)i * 1024 + lrow * 128 + swzK,
                  kb + i * 1024);
    };
    auto stageV = [&](int tile, int c) {
        char* vb = wbase + c * 8192 + 4096;
#pragma unroll
        for (int i = 0; i < 4; ++i) {
            const int u = lu ^ lrow;                    // logical unit 0..7
            const int d = i * 8 + lrow + 32 * (u >> 2); // d row 0..63
            gll16(vp + (size_t)d * 4096 + (size_t)tile * 64 + (u & 3) * 16,
                  vb + i * 1024);
        }
    };

    short8 PA[2][2];  // [kb][qt] PV B-operand fragments

    auto computeTile = [&](int c) {
        char* kb = wbase + c * 8192;
        char* vb = kb + 4096;
        short8 kf[4];
#pragma unroll
        for (int ds = 0; ds < 4; ++ds)
            kf[ds] = *(const short8*)(kb + ln5 * 128 + ((((ds * 2 + hi) << 4)) ^ sw_r));
        short8 vf[2][2];
#pragma unroll
        for (int dt = 0; dt < 2; ++dt)
#pragma unroll
            for (int k2 = 0; k2 < 2; ++k2)
                vf[dt][k2] = *(const short8*)(vb + ln5 * 128 +
                                              ((((dt * 4 + k2 * 2 + hi) << 4)) ^ sw_r));
        f32x16 s0 = {}, s1 = {};
        __builtin_amdgcn_s_setprio(1);
#pragma unroll
        for (int ds = 0; ds < 4; ++ds) {
            s0 = MFMA32(kf[ds], qf[0][ds], s0);
            s1 = MFMA32(kf[ds], qf[1][ds], s1);
        }
        __builtin_amdgcn_s_setprio(0);
        auto buildPA = [&](const f32x16& sv, float& lacc, short8& oA, short8& oB) {
            float p[16];
#pragma unroll
            for (int e = 0; e < 16; ++e) p[e] = fast_exp2(sv[e]);
            float t0 = 0.f, t1 = 0.f;
#pragma unroll
            for (int e = 0; e < 16; e += 2) { t0 += p[e]; t1 += p[e + 1]; }
            lacc += t0 + t1;
            unsigned c0 = cvtpk(p[0], p[1]),   c1 = cvtpk(p[2], p[3]);
            unsigned c2 = cvtpk(p[4], p[5]),   c3 = cvtpk(p[6], p[7]);
            unsigned c4 = cvtpk(p[8], p[9]),   c5 = cvtpk(p[10], p[11]);
            unsigned c6 = cvtpk(p[12], p[13]), c7 = cvtpk(p[14], p[15]);
            pl32(c0, c2); pl32(c1, c3);
            pl32(c4, c6); pl32(c5, c7);
            union U { short8 s8; unsigned u[4]; };
            U a; a.u[0] = c0; a.u[1] = c1; a.u[2] = c2; a.u[3] = c3; oA = a.s8;
            U b; b.u[0] = c4; b.u[1] = c5; b.u[2] = c6; b.u[3] = c7; oB = b.s8;
        };
        buildPA(s0, lp0, PA[0][0], PA[1][0]);
        buildPA(s1, lp1, PA[0][1], PA[1][1]);
        __builtin_amdgcn_s_setprio(1);
#pragma unroll
        for (int dt = 0; dt < 2; ++dt)
#pragma unroll
            for (int k2 = 0; k2 < 2; ++k2) {
                O[dt][0] = MFMA32(vf[dt][k2], PA[k2][0], O[dt][0]);
                O[dt][1] = MFMA32(vf[dt][k2], PA[k2][1], O[dt][1]);
            }
        __builtin_amdgcn_s_setprio(0);
    };

    // ---- main loop: NO barriers; wave-local counted vmcnt (T4) ----
    stageK(w, 0);
    stageV(w, 0);
    int cur = 0;
    for (int t = 0; t < 16; ++t) {
        if (t < 15) {
            stageK(w + (t + 1) * 4, cur ^ 1);
            stageV(w + (t + 1) * 4, cur ^ 1);
            asm volatile("s_waitcnt vmcnt(8)" ::: "memory");
        } else {
            asm volatile("s_waitcnt vmcnt(0)" ::: "memory");
        }
        computeTile(cur);
        cur ^= 1;
    }
    __syncthreads();  // waves decoupled; merge below reuses smem

    float* lpf = (float*)smem;  // float[4][64]
    {
        const float a = lp0 + __shfl_xor(lp0, 32);
        const float b = lp1 + __shfl_xor(lp1, 32);
        if (hi == 0) {
            lpf[w * 64 + ln5] = a;
            lpf[w * 64 + 32 + ln5] = b;
        }
    }
    __syncthreads();
    const int qq = tid & 63;
    const int k8a = tid >> 6;  // 0..3
    const float den = lpf[qq] + lpf[64 + qq] + lpf[128 + qq] + lpf[192 + qq];
    const float inv = 1.0f / den;
    __syncthreads();
    float* freg = (float*)smem + w * 4096;  // wave's 16KB region: [64 d][64 q] f32
#pragma unroll
    for (int dt = 0; dt < 2; ++dt)
#pragma unroll
        for (int qt = 0; qt < 2; ++qt)
#pragma unroll
            for (int e = 0; e < 16; ++e) {
                const int d = dt * 32 + (e & 3) + 8 * (e >> 2) + 4 * hi;
                freg[d * 64 + qt * 32 + ln5] = O[dt][qt][e];
            }
    __syncthreads();
    const int b = bh >> 3, h = bh & 7;
    const float* fall = (const float*)smem;
#pragma unroll
    for (int j = 0; j < 2; ++j) {
        const int k8 = k8a + j * 4;  // 0..7
        float a8[8];
#pragma unroll
        for (int dd = 0; dd < 8; ++dd) {
            const int d = k8 * 8 + dd;
            a8[dd] = fall[d * 64 + qq] + fall[4096 + d * 64 + qq] +
                     fall[8192 + d * 64 + qq] + fall[12288 + d * 64 + qq];
        }
        short8 o8;
#pragma unroll
        for (int dd = 0; dd < 8; ++dd) o8[dd] = f2bf(a8[dd] * inv);
        *(short8*)(AwF + ((size_t)(h * 8 + k8) * 4096 + (size_t)(b * 2048 + q0 + qq)) * 8) = o8;
    }
}

// ---------- 4) output GEMM: LDS-staged (unchanged) ----------
__global__ __launch_bounds__(256) void gemm_final(const short* __restrict__ AwF,
                                                  const short* __restrict__ WoF,
                                                  const float* __restrict__ bias,
                                                  float* __restrict__ out) {
    const int tid = threadIdx.x;
    const int w = tid >> 6;
    const int lane = tid & 63;
    const int quad = lane >> 4, ln = lane & 15;
    const int wr = w >> 1, wc = w & 1;
    const int row0 = blockIdx.x * 64;
    const int col0 = blockIdx.y * 128;

    __shared__ __align__(16) short lds[2][12288];   // 48 KB

    auto stage = [&](int buf, int kt) {
        short* d = &lds[buf][0];
        const int kb0 = kt * 8;
#pragma unroll
        for (int c = 0; c < 2; ++c) {
            const int kb = c * 4 + w;
            gll16(AwF + ((size_t)(kb0 + kb) * 4096 + row0 + lane) * 8,
                  d + kb * 512);
        }
#pragma unroll
        for (int c = 0; c < 4; ++c) {
            const int g = c * 4 + w;
            const int kb = g >> 1, colb = (g & 1) * 64;
            gll16(WoF + ((size_t)(kb0 + kb) * 1024 + col0 + colb + lane) * 8,
                  d + 4096 + (kb * 128 + colb) * 8);
        }
    };

    floatx4 acc[2][4] = {};

    auto compute = [&](int buf) {
        const short* sA = &lds[buf][0];
        const short* sB = &lds[buf][4096];
#pragma unroll
        for (int s = 0; s < 2; ++s) {
            const int kb = s * 4 + quad;
            short8 aF[2], bF[4];
#pragma unroll
            for (int i = 0; i < 2; ++i)
                aF[i] = *(const short8*)(sA + (kb * 64 + wr * 32 + i * 16 + ln) * 8);
#pragma unroll
            for (int j = 0; j < 4; ++j)
                bF[j] = *(const short8*)(sB + (kb * 128 + wc * 64 + j * 16 + ln) * 8);
#pragma unroll
            for (int i = 0; i < 2; ++i)
#pragma unroll
                for (int j = 0; j < 4; ++j)
                    acc[i][j] = MFMA_BF16(aF[i], bF[j], acc[i][j]);
        }
    };

    stage(0, 0);
    __syncthreads();
    for (int t = 0; t < 8; ++t) {
        if (t + 1 < 8) stage((t + 1) & 1, t + 1);
        compute(t & 1);
        __syncthreads();
    }

#pragma unroll
    for (int i = 0; i < 2; ++i)
#pragma unroll
        for (int t = 0; t < 4; ++t)
#pragma unroll
            for (int r = 0; r < 4; ++r) {
                const int R = row0 + wr * 32 + i * 16 + quad * 4 + r;
                const int C = col0 + wc * 64 + t * 16 + ln;
                out[(size_t)R * 1024 + C] = acc[i][t][r] + bias[C];
            }
}

// ---------- launcher ----------
extern "C" void kernel_launch(void* const* d_in, const int* in_sizes, int n_in,
                              void* d_out, int out_size, void* d_ws, size_t ws_size,
                              hipStream_t stream) {
    const float* x   = (const float*)d_in[0];  // [2,2048,1024] f32
    const float* ctx = (const float*)d_in[1];
    const float* Wq  = (const float*)d_in[2];  // [1024,512]
    const float* Wk  = (const float*)d_in[3];
    const float* Wv  = (const float*)d_in[4];
    const float* Wo  = (const float*)d_in[5];  // [512,1024]
    const float* bo  = (const float*)d_in[6];  // [1024]
    float* out = (float*)d_out;                // [2,2048,1024] f32

    char* ws = (char*)d_ws;
    size_t off = 0;
    auto alloc = [&](size_t bytes) { char* p = ws + off; off += (bytes + 255) & ~(size_t)255; return p; };

    short* WqF  = (short*)alloc(512 * 1024 * 2);        // fragment-native bf16
    short* WkF  = (short*)alloc(512 * 1024 * 2);
    short* WvF  = (short*)alloc(512 * 1024 * 2);
    short* WoF  = (short*)alloc(1024 * 512 * 2);
    short* Qw   = (short*)alloc((size_t)16 * 2048 * 64 * 2);
    short* Kw   = (short*)alloc((size_t)16 * 2048 * 64 * 2);
    short* Vtw  = (short*)alloc((size_t)16 * 2048 * 64 * 2);
    short* AwF  = (short*)alloc((size_t)4096 * 512 * 2);   // attn out, native

    wfrag_all<<<dim3(256, 4), 256, 0, stream>>>(Wq, Wk, Wv, Wo, WqF, WkF, WvF, WoF);

    gemm_qkv<<<dim3(64, 4, 3), 256, 0, stream>>>(x, ctx, WqF, WkF, WvF, Qw, Kw, Vtw);

    attn_kernel<<<dim3(32, 16), 256, 0, stream>>>(Qw, Kw, Vtw, AwF);

    gemm_final<<<dim3(64, 8), 256, 0, stream>>>(AwF, WoF, bo, out);
}